// Round 3
// baseline (95.383 us; speedup 1.0000x reference)
//
#include <hip/hip_runtime.h>
#include <hip/hip_cooperative_groups.h>
#include <math.h>

namespace cg = cooperative_groups;

#define EPS 1e-7f
#define NBLK 1024

// Problem constants: B=64, C=18, na=3; scales 160/80/40.
// obj channel for anchor a is c = a*6+4 -> plane p=3b+a at offset (6p+4)*HW.
// Only boxes[63] drives the box loss / positive cell (reference keeps the
// "last image wins" bug).

__device__ __forceinline__ float softplus_fast(float x) {
    float e = __expf(-fabsf(x));
    return fmaxf(x, 0.0f) + __logf(1.0f + e);
}

// Sum softplus over the obj planes of one scale, scaled by invN.
// HW8 = H*W/8 (each index covers two adjacent float4s = 8 floats).
template <int HW8>
__device__ float scale_obj_sum(const float* __restrict__ p, int tid, int nth,
                               float invN) {
    const int NV = 192 * HW8;  // B*na groups of 8
    float acc = 0.0f;
    for (int i = tid; i < NV; i += nth) {
        int pix8  = i % HW8;       // compile-time const -> magic mul
        int plane = i / HW8;       // p = 3b+a; obj plane offset = (6p+4)*HW
        const float4* src = reinterpret_cast<const float4*>(p)
                          + (size_t)(6 * plane + 4) * (HW8 * 2)
                          + (size_t)pix8 * 2;
        float4 v0 = src[0];        // two independent 16B loads -> MLP
        float4 v1 = src[1];
        acc += softplus_fast(v0.x) + softplus_fast(v0.y)
             + softplus_fast(v0.z) + softplus_fast(v0.w)
             + softplus_fast(v1.x) + softplus_fast(v1.y)
             + softplus_fast(v1.z) + softplus_fast(v1.w);
    }
    return acc * invN;
}

__global__ __launch_bounds__(256)
void yolo_coop(const float* __restrict__ p0,
               const float* __restrict__ p1,
               const float* __restrict__ p2,
               const float* __restrict__ boxes,
               float* __restrict__ partials,
               float* __restrict__ out) {
    const int tid = blockIdx.x * blockDim.x + threadIdx.x;
    const int nth = gridDim.x * blockDim.x;
    float acc = scale_obj_sum<3200>(p0, tid, nth, 1.0f / 4915200.0f)
              + scale_obj_sum< 800>(p1, tid, nth, 1.0f / 1228800.0f)
              + scale_obj_sum< 200>(p2, tid, nth, 1.0f /  307200.0f);

    for (int off = 32; off > 0; off >>= 1) acc += __shfl_down(acc, off, 64);
    __shared__ float smem[4];
    if ((threadIdx.x & 63) == 0) smem[threadIdx.x >> 6] = acc;
    __syncthreads();
    if (threadIdx.x == 0)
        partials[blockIdx.x] = smem[0] + smem[1] + smem[2] + smem[3];

    cg::this_grid().sync();  // all partials visible; barrier self-resets

    if (blockIdx.x != 0) return;

    // --- block 0: deterministic tree-reduce of the 1024 partials
    float a2 = 0.0f;
    for (int i = threadIdx.x; i < NBLK; i += 256) a2 += partials[i];
    for (int off = 32; off > 0; off >>= 1) a2 += __shfl_down(a2, off, 64);
    if ((threadIdx.x & 63) == 0) smem[threadIdx.x >> 6] = a2;
    __syncthreads();
    if (threadIdx.x != 0) return;

    float obj_loss = smem[0] + smem[1] + smem[2] + smem[3];

    const float anch[3][3][2] = {
        {{1.25f, 1.625f}, {2.0f, 3.75f}, {4.125f, 2.875f}},
        {{1.875f, 3.8125f}, {3.875f, 2.8125f}, {3.6875f, 7.4375f}},
        {{3.625f, 2.8125f}, {4.875f, 6.1875f}, {11.65625f, 10.1875f}},
    };
    const int   dims[3] = {160, 80, 40};
    const float invN[3] = {1.0f / 4915200.0f, 1.0f / 1228800.0f,
                           1.0f / 307200.0f};
    const float* preds[3] = {p0, p1, p2};

    const float bx = boxes[63 * 4 + 0];
    const float by = boxes[63 * 4 + 1];
    const float bw = boxes[63 * 4 + 2];
    const float bh = boxes[63 * 4 + 3];

    float box_loss = 0.0f;

    for (int s = 0; s < 3; ++s) {
        const int W = dims[s], H = dims[s];
        const float gx = bx * W, gy = by * H, gw = bw * W, gh = bh * H;
        int gi = (int)gx; gi = gi < 0 ? 0 : (gi > W - 1 ? W - 1 : gi);
        int gj = (int)gy; gj = gj < 0 ? 0 : (gj > H - 1 ? H - 1 : gj);

        int best = 0; float bestv = -1e30f;
        for (int a = 0; a < 3; ++a) {
            const float aw = anch[s][a][0], ah = anch[s][a][1];
            const float inter = fminf(gw, aw) * fminf(gh, ah);
            const float uni   = gw * gh + aw * ah - inter + EPS;
            const float v = inter / uni;
            if (v > bestv) { bestv = v; best = a; }
        }

        const float* P = preds[s];
        const size_t HW = (size_t)W * H;
        const size_t base = ((size_t)63 * 18 + (size_t)best * 6) * HW
                          + (size_t)gj * W + (size_t)gi;
        const float ps0 = P[base];
        const float ps1 = P[base + HW];
        const float ps2 = P[base + 2 * HW];
        const float ps3 = P[base + 3 * HW];
        const float ps4 = P[base + 4 * HW];

        obj_loss -= ps4 * invN[s];  // remove -x*t term at the positive cell

        const float sx = 1.0f / (1.0f + expf(-ps0));
        const float sy = 1.0f / (1.0f + expf(-ps1));
        const float hw_ = expf(ps2) * anch[s][best][0] * 0.5f;
        const float hh_ = expf(ps3) * anch[s][best][1] * 0.5f;
        const float x1 = sx - hw_, y1 = sy - hh_;
        const float x2 = sx + hw_, y2 = sy + hh_;
        const float tx1 = bx - bw * 0.5f, ty1 = by - bh * 0.5f;
        const float tx2 = bx + bw * 0.5f, ty2 = by + bh * 0.5f;

        const float w1 = x2 - x1, h1 = fmaxf(y2 - y1, EPS);
        const float w2 = tx2 - tx1, h2 = fmaxf(ty2 - ty1, EPS);
        const float iw = fmaxf(fminf(x2, tx2) - fmaxf(x1, tx1), 0.0f);
        const float ih = fmaxf(fminf(y2, ty2) - fmaxf(y1, ty1), 0.0f);
        const float inter = iw * ih;
        const float uni = w1 * h1 + w2 * h2 - inter + EPS;
        const float iou = inter / uni;

        const float cw  = fmaxf(x2, tx2) - fminf(x1, tx1);
        const float chh = fmaxf(y2, ty2) - fminf(y1, ty1);
        const float ddx = tx1 + tx2 - x1 - x2;
        const float ddy = ty1 + ty2 - y1 - y2;
        const float rho2 = (ddx * ddx + ddy * ddy) * 0.25f;
        const float c2 = cw * cw + chh * chh + EPS;
        const float dw = w2 - w1, dh = h2 - h1;
        const float eiou = iou - (rho2 / c2 + dw * dw / (cw * cw + EPS)
                                           + dh * dh / (chh * chh + EPS));
        box_loss += sqrtf(iou) * (1.0f - eiou);
    }

    const float total = 0.1f * box_loss + 1.0f * obj_loss;
    out[0] = total;
    out[1] = box_loss;
    out[2] = obj_loss;
    out[3] = 0.0f;
    out[4] = total;
}

extern "C" void kernel_launch(void* const* d_in, const int* in_sizes, int n_in,
                              void* d_out, int out_size, void* d_ws,
                              size_t ws_size, hipStream_t stream) {
    const float* p0    = (const float*)d_in[0];
    const float* p1    = (const float*)d_in[1];
    const float* p2    = (const float*)d_in[2];
    const float* boxes = (const float*)d_in[3];
    float* out      = (float*)d_out;
    float* partials = (float*)d_ws;  // 1024 floats, fully rewritten each call

    void* args[] = {(void*)&p0, (void*)&p1, (void*)&p2, (void*)&boxes,
                    (void*)&partials, (void*)&out};
    hipLaunchCooperativeKernel((void*)yolo_coop, dim3(NBLK), dim3(256),
                               args, 0, stream);
}

// Round 4
// 14.579 us; speedup vs baseline: 6.5424x; 6.5424x over previous
//
#include <hip/hip_runtime.h>
#include <math.h>

#define EPS 1e-7f

// All sizes in float4 "groups". Obj channels: plane p=3b+a (b<64, a<3) lives
// at float4 offset (6p+4)*(HW/4) of its tensor.
//   scale0: 192 planes * 6400 groups = 1228800
//   scale1: 192 planes * 1600 groups =  307200   (cum 1536000)
//   scale2: 192 planes *  400 groups =   76800   (cum 1612800)
#define SEG0   1228800
#define SEG01  1536000
#define NBLK   900     // 900 blocks * 256 thr * 7 groups = 1,612,800 exactly
#define GPT    7

__device__ __forceinline__ float softplus_fast(float x) {
    float e = __expf(-fabsf(x));
    return fmaxf(x, 0.0f) + __logf(1.0f + e);
}

__global__ __launch_bounds__(256)
void yolo_main(const float* __restrict__ p0,
               const float* __restrict__ p1,
               const float* __restrict__ p2,
               const float* __restrict__ boxes,
               float* __restrict__ partials) {
    const int tid  = threadIdx.x;
    const int base = blockIdx.x * (256 * GPT);

    // --- compute 7 addresses + weights (compile-time magic divs), then issue
    // --- 7 independent 16B loads so they're all in flight together.
    const float4* src[GPT];
    float         wt[GPT];
#pragma unroll
    for (int k = 0; k < GPT; ++k) {
        const int g = base + tid + k * 256;
        if (g < SEG0) {
            const int plane = g / 6400, off = g - plane * 6400;
            src[k] = reinterpret_cast<const float4*>(p0)
                   + (size_t)(6 * plane + 4) * 6400 + off;
            wt[k] = 1.0f / 4915200.0f;
        } else if (g < SEG01) {
            const int h = g - SEG0;
            const int plane = h / 1600, off = h - plane * 1600;
            src[k] = reinterpret_cast<const float4*>(p1)
                   + (size_t)(6 * plane + 4) * 1600 + off;
            wt[k] = 1.0f / 1228800.0f;
        } else {
            const int h = g - SEG01;
            const int plane = h / 400, off = h - plane * 400;
            src[k] = reinterpret_cast<const float4*>(p2)
                   + (size_t)(6 * plane + 4) * 400 + off;
            wt[k] = 1.0f / 307200.0f;
        }
    }
    float4 v[GPT];
#pragma unroll
    for (int k = 0; k < GPT; ++k) v[k] = *src[k];

    float acc = 0.0f;
#pragma unroll
    for (int k = 0; k < GPT; ++k)
        acc += wt[k] * (softplus_fast(v[k].x) + softplus_fast(v[k].y)
                      + softplus_fast(v[k].z) + softplus_fast(v[k].w));

    // --- scalar tail on block 0 / thread 0, hidden under streaming work.
    if (blockIdx.x == 0 && tid == 0) {
        const float anch[3][3][2] = {
            {{1.25f, 1.625f}, {2.0f, 3.75f}, {4.125f, 2.875f}},
            {{1.875f, 3.8125f}, {3.875f, 2.8125f}, {3.6875f, 7.4375f}},
            {{3.625f, 2.8125f}, {4.875f, 6.1875f}, {11.65625f, 10.1875f}},
        };
        const int   dims[3] = {160, 80, 40};
        const float invN[3] = {1.0f / 4915200.0f, 1.0f / 1228800.0f,
                               1.0f / 307200.0f};
        const float* preds[3] = {p0, p1, p2};

        const float bx = boxes[63 * 4 + 0];
        const float by = boxes[63 * 4 + 1];
        const float bw = boxes[63 * 4 + 2];
        const float bh = boxes[63 * 4 + 3];

        float box_loss = 0.0f;
#pragma unroll
        for (int s = 0; s < 3; ++s) {
            const int W = dims[s], H = dims[s];
            const float gx = bx * W, gy = by * H, gw = bw * W, gh = bh * H;
            int gi = (int)gx; gi = gi < 0 ? 0 : (gi > W - 1 ? W - 1 : gi);
            int gj = (int)gy; gj = gj < 0 ? 0 : (gj > H - 1 ? H - 1 : gj);

            int best = 0; float bestv = -1e30f;
            for (int a = 0; a < 3; ++a) {
                const float aw = anch[s][a][0], ah = anch[s][a][1];
                const float inter = fminf(gw, aw) * fminf(gh, ah);
                const float uni   = gw * gh + aw * ah - inter + EPS;
                const float val = inter / uni;
                if (val > bestv) { bestv = val; best = a; }
            }

            const float* P = preds[s];
            const size_t HW = (size_t)W * H;
            const size_t b0 = ((size_t)63 * 18 + (size_t)best * 6) * HW
                            + (size_t)gj * W + (size_t)gi;
            const float ps0 = P[b0];
            const float ps1 = P[b0 + HW];
            const float ps2 = P[b0 + 2 * HW];
            const float ps3 = P[b0 + 3 * HW];
            const float ps4 = P[b0 + 4 * HW];

            acc -= ps4 * invN[s];  // remove -x*t at the positive cell

            const float sx = 1.0f / (1.0f + expf(-ps0));
            const float sy = 1.0f / (1.0f + expf(-ps1));
            const float hw_ = expf(ps2) * anch[s][best][0] * 0.5f;
            const float hh_ = expf(ps3) * anch[s][best][1] * 0.5f;
            const float x1 = sx - hw_, y1 = sy - hh_;
            const float x2 = sx + hw_, y2 = sy + hh_;
            const float tx1 = bx - bw * 0.5f, ty1 = by - bh * 0.5f;
            const float tx2 = bx + bw * 0.5f, ty2 = by + bh * 0.5f;

            const float w1 = x2 - x1, h1 = fmaxf(y2 - y1, EPS);
            const float w2 = tx2 - tx1, h2 = fmaxf(ty2 - ty1, EPS);
            const float iw = fmaxf(fminf(x2, tx2) - fmaxf(x1, tx1), 0.0f);
            const float ih = fmaxf(fminf(y2, ty2) - fmaxf(y1, ty1), 0.0f);
            const float inter = iw * ih;
            const float uni = w1 * h1 + w2 * h2 - inter + EPS;
            const float iou = inter / uni;

            const float cw  = fmaxf(x2, tx2) - fminf(x1, tx1);
            const float chh = fmaxf(y2, ty2) - fminf(y1, ty1);
            const float ddx = tx1 + tx2 - x1 - x2;
            const float ddy = ty1 + ty2 - y1 - y2;
            const float rho2 = (ddx * ddx + ddy * ddy) * 0.25f;
            const float c2 = cw * cw + chh * chh + EPS;
            const float dw = w2 - w1, dh = h2 - h1;
            const float eiou = iou - (rho2 / c2 + dw * dw / (cw * cw + EPS)
                                               + dh * dh / (chh * chh + EPS));
            box_loss += sqrtf(iou) * (1.0f - eiou);
        }
        partials[NBLK] = box_loss;
    }

    // --- block reduction
    for (int off = 32; off > 0; off >>= 1) acc += __shfl_down(acc, off, 64);
    __shared__ float smem[4];
    if ((tid & 63) == 0) smem[tid >> 6] = acc;
    __syncthreads();
    if (tid == 0)
        partials[blockIdx.x] = smem[0] + smem[1] + smem[2] + smem[3];
}

__global__ __launch_bounds__(256)
void yolo_fin(const float* __restrict__ partials, float* __restrict__ out) {
    float a = 0.0f;
    for (int i = threadIdx.x; i < NBLK; i += 256) a += partials[i];
    for (int off = 32; off > 0; off >>= 1) a += __shfl_down(a, off, 64);
    __shared__ float smem[4];
    if ((threadIdx.x & 63) == 0) smem[threadIdx.x >> 6] = a;
    __syncthreads();
    if (threadIdx.x != 0) return;

    const float obj_loss = smem[0] + smem[1] + smem[2] + smem[3];
    const float box_loss = partials[NBLK];
    const float total = 0.1f * box_loss + 1.0f * obj_loss;
    out[0] = total;
    out[1] = box_loss;
    out[2] = obj_loss;
    out[3] = 0.0f;
    out[4] = total;
}

extern "C" void kernel_launch(void* const* d_in, const int* in_sizes, int n_in,
                              void* d_out, int out_size, void* d_ws,
                              size_t ws_size, hipStream_t stream) {
    const float* p0    = (const float*)d_in[0];
    const float* p1    = (const float*)d_in[1];
    const float* p2    = (const float*)d_in[2];
    const float* boxes = (const float*)d_in[3];
    float* out      = (float*)d_out;
    float* partials = (float*)d_ws;  // 901 floats, fully rewritten each call

    yolo_main<<<NBLK, 256, 0, stream>>>(p0, p1, p2, boxes, partials);
    yolo_fin<<<1, 256, 0, stream>>>(partials, out);
}

// Round 5
// 13.297 us; speedup vs baseline: 7.1733x; 1.0964x over previous
//
#include <hip/hip_runtime.h>
#include <math.h>

#define EPS 1e-7f

// All sizes in float4 "groups". Obj channels: plane p=3b+a (b<64, a<3) lives
// at float4 offset (6p+4)*(HW/4) of its tensor.
//   scale0: 192 planes * 6400 groups = 1228800
//   scale1: 192 planes * 1600 groups =  307200   (cum 1536000)
//   scale2: 192 planes *  400 groups =   76800   (cum 1612800)
#define SEG0   1228800
#define SEG01  1536000
#define NBLK   225     // 225 blocks * 1024 thr * 7 groups = 1,612,800 exactly
#define BTHR   1024
#define GPT    7

__device__ __forceinline__ float softplus_fast(float x) {
    float e = __expf(-fabsf(x));
    return fmaxf(x, 0.0f) + __logf(1.0f + e);
}

__global__ __launch_bounds__(BTHR)
void yolo_main(const float* __restrict__ p0,
               const float* __restrict__ p1,
               const float* __restrict__ p2,
               const float* __restrict__ boxes,
               float* __restrict__ partials) {
    const int tid  = threadIdx.x;
    const int base = blockIdx.x * (BTHR * GPT);

    // 7 addresses + weights (compile-time magic divs), then 7 independent
    // 16B loads so they are all in flight together.
    const float4* src[GPT];
    float         wt[GPT];
#pragma unroll
    for (int k = 0; k < GPT; ++k) {
        const int g = base + tid + k * BTHR;
        if (g < SEG0) {
            const int plane = g / 6400, off = g - plane * 6400;
            src[k] = reinterpret_cast<const float4*>(p0)
                   + (size_t)(6 * plane + 4) * 6400 + off;
            wt[k] = 1.0f / 4915200.0f;
        } else if (g < SEG01) {
            const int h = g - SEG0;
            const int plane = h / 1600, off = h - plane * 1600;
            src[k] = reinterpret_cast<const float4*>(p1)
                   + (size_t)(6 * plane + 4) * 1600 + off;
            wt[k] = 1.0f / 1228800.0f;
        } else {
            const int h = g - SEG01;
            const int plane = h / 400, off = h - plane * 400;
            src[k] = reinterpret_cast<const float4*>(p2)
                   + (size_t)(6 * plane + 4) * 400 + off;
            wt[k] = 1.0f / 307200.0f;
        }
    }
    float4 v[GPT];
#pragma unroll
    for (int k = 0; k < GPT; ++k) v[k] = *src[k];

    float acc = 0.0f;
#pragma unroll
    for (int k = 0; k < GPT; ++k)
        acc += wt[k] * (softplus_fast(v[k].x) + softplus_fast(v[k].y)
                      + softplus_fast(v[k].z) + softplus_fast(v[k].w));

    // --- scalar tail on block 0 / thread 0, hidden under streaming work.
    if (blockIdx.x == 0 && tid == 0) {
        const float anch[3][3][2] = {
            {{1.25f, 1.625f}, {2.0f, 3.75f}, {4.125f, 2.875f}},
            {{1.875f, 3.8125f}, {3.875f, 2.8125f}, {3.6875f, 7.4375f}},
            {{3.625f, 2.8125f}, {4.875f, 6.1875f}, {11.65625f, 10.1875f}},
        };
        const int   dims[3] = {160, 80, 40};
        const float invN[3] = {1.0f / 4915200.0f, 1.0f / 1228800.0f,
                               1.0f / 307200.0f};
        const float* preds[3] = {p0, p1, p2};

        const float bx = boxes[63 * 4 + 0];
        const float by = boxes[63 * 4 + 1];
        const float bw = boxes[63 * 4 + 2];
        const float bh = boxes[63 * 4 + 3];

        float box_loss = 0.0f;
#pragma unroll
        for (int s = 0; s < 3; ++s) {
            const int W = dims[s], H = dims[s];
            const float gx = bx * W, gy = by * H, gw = bw * W, gh = bh * H;
            int gi = (int)gx; gi = gi < 0 ? 0 : (gi > W - 1 ? W - 1 : gi);
            int gj = (int)gy; gj = gj < 0 ? 0 : (gj > H - 1 ? H - 1 : gj);

            int best = 0; float bestv = -1e30f;
            for (int a = 0; a < 3; ++a) {
                const float aw = anch[s][a][0], ah = anch[s][a][1];
                const float inter = fminf(gw, aw) * fminf(gh, ah);
                const float uni   = gw * gh + aw * ah - inter + EPS;
                const float val = inter / uni;
                if (val > bestv) { bestv = val; best = a; }
            }

            const float* P = preds[s];
            const size_t HW = (size_t)W * H;
            const size_t b0 = ((size_t)63 * 18 + (size_t)best * 6) * HW
                            + (size_t)gj * W + (size_t)gi;
            const float ps0 = P[b0];
            const float ps1 = P[b0 + HW];
            const float ps2 = P[b0 + 2 * HW];
            const float ps3 = P[b0 + 3 * HW];
            const float ps4 = P[b0 + 4 * HW];

            acc -= ps4 * invN[s];  // remove -x*t at the positive cell

            const float sx = 1.0f / (1.0f + expf(-ps0));
            const float sy = 1.0f / (1.0f + expf(-ps1));
            const float hw_ = expf(ps2) * anch[s][best][0] * 0.5f;
            const float hh_ = expf(ps3) * anch[s][best][1] * 0.5f;
            const float x1 = sx - hw_, y1 = sy - hh_;
            const float x2 = sx + hw_, y2 = sy + hh_;
            const float tx1 = bx - bw * 0.5f, ty1 = by - bh * 0.5f;
            const float tx2 = bx + bw * 0.5f, ty2 = by + bh * 0.5f;

            const float w1 = x2 - x1, h1 = fmaxf(y2 - y1, EPS);
            const float w2 = tx2 - tx1, h2 = fmaxf(ty2 - ty1, EPS);
            const float iw = fmaxf(fminf(x2, tx2) - fmaxf(x1, tx1), 0.0f);
            const float ih = fmaxf(fminf(y2, ty2) - fmaxf(y1, ty1), 0.0f);
            const float inter = iw * ih;
            const float uni = w1 * h1 + w2 * h2 - inter + EPS;
            const float iou = inter / uni;

            const float cw  = fmaxf(x2, tx2) - fminf(x1, tx1);
            const float chh = fmaxf(y2, ty2) - fminf(y1, ty1);
            const float ddx = tx1 + tx2 - x1 - x2;
            const float ddy = ty1 + ty2 - y1 - y2;
            const float rho2 = (ddx * ddx + ddy * ddy) * 0.25f;
            const float c2 = cw * cw + chh * chh + EPS;
            const float dw = w2 - w1, dh = h2 - h1;
            const float eiou = iou - (rho2 / c2 + dw * dw / (cw * cw + EPS)
                                               + dh * dh / (chh * chh + EPS));
            box_loss += sqrtf(iou) * (1.0f - eiou);
        }
        partials[NBLK] = box_loss;
    }

    // --- block reduction (16 waves)
    for (int off = 32; off > 0; off >>= 1) acc += __shfl_down(acc, off, 64);
    __shared__ float smem[16];
    if ((tid & 63) == 0) smem[tid >> 6] = acc;
    __syncthreads();
    if (tid < 64) {
        float a2 = (tid < 16) ? smem[tid] : 0.0f;
        for (int off = 8; off > 0; off >>= 1) a2 += __shfl_down(a2, off, 64);
        if (tid == 0) partials[blockIdx.x] = a2;
    }
}

__global__ __launch_bounds__(256)
void yolo_fin(const float* __restrict__ partials, float* __restrict__ out) {
    float a = 0.0f;
    for (int i = threadIdx.x; i < NBLK; i += 256) a += partials[i];
    for (int off = 32; off > 0; off >>= 1) a += __shfl_down(a, off, 64);
    __shared__ float smem[4];
    if ((threadIdx.x & 63) == 0) smem[threadIdx.x >> 6] = a;
    __syncthreads();
    if (threadIdx.x != 0) return;

    const float obj_loss = smem[0] + smem[1] + smem[2] + smem[3];
    const float box_loss = partials[NBLK];
    const float total = 0.1f * box_loss + 1.0f * obj_loss;
    out[0] = total;
    out[1] = box_loss;
    out[2] = obj_loss;
    out[3] = 0.0f;
    out[4] = total;
}

extern "C" void kernel_launch(void* const* d_in, const int* in_sizes, int n_in,
                              void* d_out, int out_size, void* d_ws,
                              size_t ws_size, hipStream_t stream) {
    const float* p0    = (const float*)d_in[0];
    const float* p1    = (const float*)d_in[1];
    const float* p2    = (const float*)d_in[2];
    const float* boxes = (const float*)d_in[3];
    float* out      = (float*)d_out;
    float* partials = (float*)d_ws;  // 226 floats, fully rewritten each call

    yolo_main<<<NBLK, BTHR, 0, stream>>>(p0, p1, p2, boxes, partials);
    yolo_fin<<<1, 256, 0, stream>>>(partials, out);
}